// Round 1
// baseline (320.545 us; speedup 1.0000x reference)
//
#include <hip/hip_runtime.h>
#include <hip/hip_bf16.h>

// ModulatedConv2d, B=16, Cin=Cout=512, 3x3, 64x64, style_dim=512.
// Decomposition: out = deco[b,o] * conv2d(x*s[b,i], W*gain)  (weights shared across batch)
// ws layout (needs ~70MB):
//   s    : f32[16*512]            @ 0
//   deco : f32[16*512]            @ 32768
//   q    : f32[512*512]           @ 65536
//   wb   : bf16[512][9][512]      @ 65536+1048576          (o, tap, ci) ci-inner
//   xs   : bf16[16][64][64][512]  @ 65536+1048576+4718592  (b, y, x, ci) NHWC

#define NB   16
#define NCH  512
#define NH   64
#define NW   64

static constexpr float FC_GAIN_C = 0.04419417382415922f;   // 1/sqrt(512)
static constexpr float W_GAIN_C  = 0.014731391274719742f;  // 1/sqrt(512*9)

typedef float        f32x4 __attribute__((ext_vector_type(4)));
typedef short        s16x8 __attribute__((ext_vector_type(8)));
typedef unsigned int u32x4 __attribute__((ext_vector_type(4)));

__device__ __forceinline__ unsigned short f2bf(float f) {
    __hip_bfloat16 h = __float2bfloat16(f);
    return *reinterpret_cast<unsigned short*>(&h);
}

// ---------------- K1: s[b,i] = style[b,:] . fc_w[i,:] * FC_GAIN + fc_b[i] ----------------
__global__ void calc_s_kernel(const float* __restrict__ style,
                              const float* __restrict__ fc_w,
                              const float* __restrict__ fc_b,
                              float* __restrict__ s) {
    int gw   = (blockIdx.x * blockDim.x + threadIdx.x) >> 6;   // 8192 waves
    int lane = threadIdx.x & 63;
    int b = gw >> 9;
    int i = gw & 511;
    const float* st = style + b * NCH;
    const float* fw = fc_w + (size_t)i * NCH;
    float sum = 0.f;
    #pragma unroll
    for (int k = 0; k < NCH / 64; ++k)
        sum += st[lane + 64 * k] * fw[lane + 64 * k];
    #pragma unroll
    for (int off = 32; off >= 1; off >>= 1)
        sum += __shfl_xor(sum, off, 64);
    if (lane == 0)
        s[b * NCH + i] = sum * FC_GAIN_C + fc_b[i];
}

// ---------------- K2: q[o,i] = G^2 * sum_t w^2 ; wb[(o*9+t)*512+i] = bf16(w*G) ----------
__global__ void calc_q_wb_kernel(const float* __restrict__ weight,
                                 float* __restrict__ q,
                                 unsigned short* __restrict__ wb) {
    int o = blockIdx.x;
    int i = threadIdx.x;
    const float* wp = weight + ((size_t)o * NCH + i) * 9;
    float qs = 0.f;
    #pragma unroll
    for (int t = 0; t < 9; ++t) {
        float v = wp[t] * W_GAIN_C;
        qs += v * v;
        wb[((size_t)o * 9 + t) * NCH + i] = f2bf(v);
    }
    q[(size_t)o * NCH + i] = qs;
}

// ---------------- K3: deco[b,o] = rsqrt( sum_i q[o,i]*s[b,i]^2 + 1e-8 ) -----------------
__global__ void calc_deco_kernel(const float* __restrict__ q,
                                 const float* __restrict__ s,
                                 float* __restrict__ deco) {
    int gw   = (blockIdx.x * blockDim.x + threadIdx.x) >> 6;
    int lane = threadIdx.x & 63;
    int b = gw >> 9;
    int o = gw & 511;
    const float* qp = q + (size_t)o * NCH;
    const float* sp = s + b * NCH;
    float sum = 0.f;
    #pragma unroll
    for (int k = 0; k < NCH / 64; ++k) {
        float sv = sp[lane + 64 * k];
        sum += qp[lane + 64 * k] * sv * sv;
    }
    #pragma unroll
    for (int off = 32; off >= 1; off >>= 1)
        sum += __shfl_xor(sum, off, 64);
    if (lane == 0)
        deco[b * NCH + o] = rsqrtf(sum + 1e-8f);
}

// ---------------- K4: xs[b,y,x,i] = bf16( x[b,i,y,x] * s[b,i] )  (NCHW->NHWC) ------------
__global__ void scale_x_kernel(const float* __restrict__ x,
                               const float* __restrict__ s,
                               unsigned short* __restrict__ xs) {
    __shared__ unsigned short tl[NW * 32];
    int blk = blockIdx.x;
    int c0  = blk & 15;          // channel chunk (32 ch)
    int y   = (blk >> 4) & 63;
    int b   = blk >> 10;
    int t   = threadIdx.x;
    {
        int c  = t >> 3;          // 0..31
        int xq = (t & 7) * 8;     // 0..56
        int ch = c0 * 32 + c;
        const float* xp = x + (((size_t)(b * NCH + ch) * NH + y) * NW + xq);
        float sv = s[b * NCH + ch];
        f32x4 a0 = *(const f32x4*)xp;
        f32x4 a1 = *(const f32x4*)(xp + 4);
        #pragma unroll
        for (int j = 0; j < 4; ++j) {
            tl[(xq + j) * 32 + c]     = f2bf(a0[j] * sv);
            tl[(xq + 4 + j) * 32 + c] = f2bf(a1[j] * sv);
        }
    }
    __syncthreads();
    {
        int xc = t >> 2;          // 0..63
        int co = (t & 3) * 8;     // 0..24
        u32x4 v = *(const u32x4*)&tl[xc * 32 + co];
        *(u32x4*)&xs[((size_t)(b * NH + y) * NW + xc) * NCH + c0 * 32 + co] = v;
    }
}

// ---------------- K5: implicit-GEMM conv with bf16 MFMA ----------------------------------
// Block: one (batch, 64-o tile, 4-row tile). 4 waves, wave w = output row y0+w,
// each wave 64(o) x 64(x) output = 4x4 MFMA frags. K loop: 16 chunks of 32 channels,
// inner loop 9 taps, mfma_f32_16x16x32_bf16.
// LDS (XOR-swizzled 16B granules, unpadded): W [64][9*32], X [6 rows][66 cols][32 ch].
__global__ __launch_bounds__(256, 2)
void conv_kernel(const unsigned short* __restrict__ xs,
                 const unsigned short* __restrict__ wb,
                 const float* __restrict__ deco,
                 float* __restrict__ out) {
    __shared__ unsigned short w_lds[64 * 288];      // 36,864 B
    __shared__ unsigned short x_lds[6 * 66 * 32];   // 25,344 B

    int tid  = threadIdx.x;
    int lane = tid & 63;
    int wave = tid >> 6;        // 0..3 -> output row y0+wave
    int lg   = lane >> 4;       // 0..3 (k-group)
    int lr   = lane & 15;

    int blk = blockIdx.x;
    int bi  = blk & 15;
    int ot  = (blk >> 4) & 7;
    int yt  = blk >> 7;
    int o0  = ot * 64;
    int y0  = yt * 4;

    // zero x_lds once: halo cols (0,65) and out-of-image rows stay 0 forever
    {
        u32x4 z = {0u, 0u, 0u, 0u};
        for (int idx = tid * 8; idx < 6 * 66 * 32; idx += 256 * 8)
            *(u32x4*)&x_lds[idx] = z;
    }

    // precompute staging offsets (swizzle folded in)
    int wls[9], wgo[9];
    #pragma unroll
    for (int it = 0; it < 9; ++it) {
        int idx = it * 256 + tid;      // 0..2303 = (o,tap,c8)
        int c8  = idx & 3;
        int q4  = idx >> 2;
        int tap = q4 % 9;
        int o   = q4 / 9;
        wls[it] = o * 288 + tap * 32 + (c8 ^ ((o >> 1) & 3)) * 8;
        wgo[it] = (o * 9 + tap) * NCH + c8 * 8;
    }
    int xls[6], xgo[6];
    bool xok[6];
    #pragma unroll
    for (int it = 0; it < 6; ++it) {
        int idx = it * 256 + tid;      // 0..1535 = (r,col,c8)
        int c8  = idx & 3;
        int col = (idx >> 2) & 63;
        int r   = idx >> 8;            // 0..5
        int gy  = y0 - 1 + r;
        int P   = r * 66 + col + 1;
        xok[it] = (gy >= 0 && gy < NH);
        xls[it] = P * 32 + (c8 ^ ((P >> 1) & 3)) * 8;
        xgo[it] = (gy * NW + col) * NCH + c8 * 8;
    }

    const unsigned short* xsb = xs + (size_t)bi * NH * NW * NCH;
    const unsigned short* wsb = wb + (size_t)o0 * 9 * NCH;

    f32x4 acc[4][4];
    #pragma unroll
    for (int mi = 0; mi < 4; ++mi)
        #pragma unroll
        for (int ni = 0; ni < 4; ++ni)
            #pragma unroll
            for (int k = 0; k < 4; ++k) acc[mi][ni][k] = 0.f;

    int ag = (lg ^ ((lr >> 1) & 3)) * 8;   // A-frag swizzle is lane-constant

    for (int chunk = 0; chunk < 16; ++chunk) {
        int i0 = chunk * 32;
        __syncthreads();
        u32x4 wv[9], xv[6];
        #pragma unroll
        for (int it = 0; it < 9; ++it)
            wv[it] = *(const u32x4*)(wsb + i0 + wgo[it]);
        u32x4 z = {0u, 0u, 0u, 0u};
        #pragma unroll
        for (int it = 0; it < 6; ++it)
            xv[it] = xok[it] ? *(const u32x4*)(xsb + i0 + xgo[it]) : z;
        #pragma unroll
        for (int it = 0; it < 9; ++it)
            *(u32x4*)&w_lds[wls[it]] = wv[it];
        #pragma unroll
        for (int it = 0; it < 6; ++it)
            if (xok[it]) *(u32x4*)&x_lds[xls[it]] = xv[it];
        __syncthreads();

        #pragma unroll
        for (int t = 0; t < 9; ++t) {
            int rr = wave + t / 3;            // x_lds row
            int dx = t % 3;                   // col shift (x + dx - 1, stored +1)
            int P0 = rr * 66 + lr + dx;
            int bg = (lg ^ ((P0 >> 1) & 3)) * 8;   // B swizzle: ni-independent
            s16x8 afr[4], bfr[4];
            #pragma unroll
            for (int mi = 0; mi < 4; ++mi)
                afr[mi] = *(const s16x8*)&w_lds[(mi * 16 + lr) * 288 + t * 32 + ag];
            #pragma unroll
            for (int ni = 0; ni < 4; ++ni)
                bfr[ni] = *(const s16x8*)&x_lds[(P0 + ni * 16) * 32 + bg];
            #pragma unroll
            for (int mi = 0; mi < 4; ++mi)
                #pragma unroll
                for (int ni = 0; ni < 4; ++ni)
                    acc[mi][ni] = __builtin_amdgcn_mfma_f32_16x16x32_bf16(
                        afr[mi], bfr[ni], acc[mi][ni], 0, 0, 0);
        }
    }

    // epilogue: scale by deco and store f32
    int y = y0 + wave;
    const float* dcp = deco + bi * NCH + o0;
    #pragma unroll
    for (int mi = 0; mi < 4; ++mi) {
        #pragma unroll
        for (int r = 0; r < 4; ++r) {
            int ol = mi * 16 + lg * 4 + r;
            float dc = dcp[ol];
            float* orow = out + ((size_t)(bi * NCH + o0 + ol) * NH + y) * NW;
            #pragma unroll
            for (int ni = 0; ni < 4; ++ni)
                orow[ni * 16 + lr] = acc[mi][ni][r] * dc;
        }
    }
}

extern "C" void kernel_launch(void* const* d_in, const int* in_sizes, int n_in,
                              void* d_out, int out_size, void* d_ws, size_t ws_size,
                              hipStream_t stream) {
    const float* x      = (const float*)d_in[0];
    const float* style  = (const float*)d_in[1];
    const float* weight = (const float*)d_in[2];
    const float* fc_w   = (const float*)d_in[3];
    const float* fc_b   = (const float*)d_in[4];
    float* out = (float*)d_out;

    char* ws = (char*)d_ws;
    float* s    = (float*)(ws);
    float* deco = (float*)(ws + 32768);
    float* q    = (float*)(ws + 65536);
    unsigned short* wb = (unsigned short*)(ws + 65536 + 1048576);
    unsigned short* xs = (unsigned short*)(ws + 65536 + 1048576 + 4718592);
    // total ws use: ~70 MB

    calc_s_kernel<<<2048, 256, 0, stream>>>(style, fc_w, fc_b, s);
    calc_q_wb_kernel<<<512, 512, 0, stream>>>(weight, q, wb);
    calc_deco_kernel<<<2048, 256, 0, stream>>>(q, s, deco);
    scale_x_kernel<<<16384, 256, 0, stream>>>(x, s, xs);
    conv_kernel<<<2048, 256, 0, stream>>>(xs, wb, deco, out);
}

// Round 2
// 301.163 us; speedup vs baseline: 1.0644x; 1.0644x over previous
//
#include <hip/hip_runtime.h>
#include <hip/hip_bf16.h>

// ModulatedConv2d B=16, Cin=Cout=512, 3x3, 64x64.
// out = deco[b,o] * conv2d(x*s[b,i], W*gain), weights shared across batch.
// Conv: 32x32x16 bf16 MFMA, per-wave 128(o)x64(x), 8 waves = 8 output rows,
// chunk = 16 channels, double-buffered LDS staged via global_load_lds,
// one raw s_barrier + vmcnt(0) per chunk (counted-wait pipeline).
//
// ws layout:
//   s    : f32[16*512]                 @ 0
//   deco : f32[16*512]                 @ 32768
//   q    : f32[512*512]                @ 65536
//   wb2  : bf16, pre-swizzled W slots  @ 1114112   (4 ot x 32 chunk x 2304 slots x 16B)
//   xs2  : bf16, pre-swizzled X slots  @ 5832704   (16 b x 32 chunk x 64 y x 128 slots x 16B)

#define NCH 512

static constexpr float FC_GAIN_C = 0.04419417382415922f;   // 1/sqrt(512)
static constexpr float W_GAIN_C  = 0.014731391274719742f;  // 1/sqrt(512*9)

typedef float        f32x4  __attribute__((ext_vector_type(4)));
typedef float        f32x16 __attribute__((ext_vector_type(16)));
typedef short        s16x8  __attribute__((ext_vector_type(8)));
typedef unsigned int u32x4  __attribute__((ext_vector_type(4)));

__device__ __forceinline__ unsigned short f2bf(float f) {
    __hip_bfloat16 h = __float2bfloat16(f);
    return *reinterpret_cast<unsigned short*>(&h);
}

__device__ __forceinline__ void gld16(const void* g, void* l) {
    __builtin_amdgcn_global_load_lds(
        (const __attribute__((address_space(1))) unsigned int*)g,
        (__attribute__((address_space(3))) unsigned int*)(l), 16, 0, 0);
}

// ---------------- K1: s[b,i] = style[b,:] . fc_w[i,:] * FC_GAIN + fc_b[i] ----------------
__global__ void calc_s_kernel(const float* __restrict__ style,
                              const float* __restrict__ fc_w,
                              const float* __restrict__ fc_b,
                              float* __restrict__ s) {
    int gw   = (blockIdx.x * blockDim.x + threadIdx.x) >> 6;
    int lane = threadIdx.x & 63;
    int b = gw >> 9;
    int i = gw & 511;
    const float* st = style + b * NCH;
    const float* fw = fc_w + (size_t)i * NCH;
    float sum = 0.f;
    #pragma unroll
    for (int k = 0; k < NCH / 64; ++k)
        sum += st[lane + 64 * k] * fw[lane + 64 * k];
    #pragma unroll
    for (int off = 32; off >= 1; off >>= 1)
        sum += __shfl_xor(sum, off, 64);
    if (lane == 0)
        s[b * NCH + i] = sum * FC_GAIN_C + fc_b[i];
}

// ---------------- K2: q[o,i] and pre-swizzled wb2 slots ----------------------------------
// wb2 slot layout per (ot, chunk): slot = o_rel*18 + t*2 + g', 16B slots.
// slot (o,t,g') holds W granule (g' ^ ((o>>2)&1)), so linear DMA + swizzled read works.
__global__ void calc_q_wb2_kernel(const float* __restrict__ weight,
                                  float* __restrict__ q,
                                  unsigned short* __restrict__ wb2) {
    int o = blockIdx.x;        // 0..511
    int i = threadIdx.x;       // 0..511 (ci)
    int orel = o & 127, ot = o >> 7;
    int chunk = i >> 4, hh = (i >> 3) & 1, e = i & 7;
    int gsw = hh ^ ((orel >> 2) & 1);
    const float* wp = weight + ((size_t)o * NCH + i) * 9;
    float qs = 0.f;
    #pragma unroll
    for (int t = 0; t < 9; ++t) {
        float v = wp[t] * W_GAIN_C;
        qs += v * v;
        wb2[(((size_t)(ot * 32 + chunk) * 2304) + orel * 18 + t * 2 + gsw) * 8 + e] = f2bf(v);
    }
    q[(size_t)o * NCH + i] = qs;
}

// ---------------- K3: deco[b,o] = rsqrt( sum_i q[o,i]*s[b,i]^2 + 1e-8 ) -----------------
__global__ void calc_deco_kernel(const float* __restrict__ q,
                                 const float* __restrict__ s,
                                 float* __restrict__ deco) {
    int gw   = (blockIdx.x * blockDim.x + threadIdx.x) >> 6;
    int lane = threadIdx.x & 63;
    int b = gw >> 9;
    int o = gw & 511;
    const float* qp = q + (size_t)o * NCH;
    const float* sp = s + b * NCH;
    float sum = 0.f;
    #pragma unroll
    for (int k = 0; k < NCH / 64; ++k) {
        float sv = sp[lane + 64 * k];
        sum += qp[lane + 64 * k] * sv * sv;
    }
    #pragma unroll
    for (int off = 32; off >= 1; off >>= 1)
        sum += __shfl_xor(sum, off, 64);
    if (lane == 0)
        deco[b * NCH + o] = rsqrtf(sum + 1e-8f);
}

// ---------------- K4: xs2 = bf16(x * s), NCHW -> per-chunk slot layout --------------------
// xs2 unit index: ((b*32+chunk)*64 + y)*128 + s ; s in [0,128): xpos = s>>1, h = s&1,
// content = x granule (ch = chunk*16 + (h ^ (((xpos+1)>>2)&1))*8 + e) at (y, xpos).
__global__ __launch_bounds__(256)
void scale_x2_kernel(const float* __restrict__ x, const float* __restrict__ s,
                     unsigned short* __restrict__ xs2) {
    __shared__ float tlf[2][64][17];
    int blk = blockIdx.x;          // 512 = bi*32 + chunk
    int chunk = blk & 31, bi = blk >> 5;
    int t = threadIdx.x;
    int ch0 = chunk * 16;
    int cl = t >> 4, xq = (t & 15) * 4;
    float sv = s[bi * NCH + ch0 + cl];
    const float* xp = x + ((size_t)(bi * NCH + ch0 + cl)) * 4096 + xq;
    int p = t >> 7, tt = t & 127;
    int xpos = tt >> 1, h = tt & 1;
    int hs = h ^ (((xpos + 1) >> 2) & 1);
    unsigned short* xout = xs2 + (size_t)(bi * 32 + chunk) * 64 * 128 * 8;
    for (int y2 = 0; y2 < 64; y2 += 2) {
        f32x4 a0 = *(const f32x4*)(xp + (size_t)y2 * 64);
        f32x4 a1 = *(const f32x4*)(xp + (size_t)(y2 + 1) * 64);
        #pragma unroll
        for (int j = 0; j < 4; ++j) {
            tlf[0][xq + j][cl] = a0[j] * sv;
            tlf[1][xq + j][cl] = a1[j] * sv;
        }
        __syncthreads();
        const float* src = &tlf[p][xpos][hs * 8];
        u32x4 v;
        #pragma unroll
        for (int j = 0; j < 4; ++j)
            v[j] = (unsigned)f2bf(src[2 * j]) | ((unsigned)f2bf(src[2 * j + 1]) << 16);
        *(u32x4*)(xout + ((size_t)(y2 + p) * 128 + tt) * 8) = v;
        __syncthreads();
    }
}

// ---------------- K5: conv, 32x32x16 MFMA, dbuf LDS + global_load_lds pipeline ------------
// block: (bi, ot, yt) -> o-tile 128, rows y0..y0+7, 8 waves (wave = row), 512 thr.
// LDS buffer: W [128o][9t][16ch] = 36864 B, X [10r][66c][16ch] = 21120 B; x2 = 115968 B.
#define W_SH 18432   // shorts per W buffer
#define X_SH 10560   // shorts per X buffer

#define ISSUE(nc, WN, XN)                                                          \
    {                                                                              \
        _Pragma("unroll") for (int j = 0; j < 5; ++j) {                            \
            int id = wave + j * 8;                                                 \
            if (id < 36)                                                           \
                gld16(wsrc + ((size_t)(nc) * 2304 + id * 64 + lane) * 16,          \
                      (WN) + id * 512);                                            \
        }                                                                          \
        _Pragma("unroll") for (int j = 0; j < 3; ++j) {                            \
            int id = wave + j * 8;                                                 \
            if (id < 20) {                                                         \
                int r_ = id >> 1, hf = id & 1, gy = y0 - 1 + r_;                   \
                if (gy >= 0 && gy < 64)                                            \
                    gld16(xsrc + (((size_t)(nc) * 64 + gy) * 128 + hf * 64 + lane) * 16, \
                          (XN) + r_ * 1056 + hf * 512 + 16);                       \
            }                                                                      \
        }                                                                          \
    }

#define COMPUTE(WC, XC)                                                            \
    {                                                                              \
        _Pragma("unroll") for (int t = 0; t < 9; ++t) {                            \
            const int rr = wave + t / 3, dx = t % 3;                               \
            const unsigned short* bp = (XC) + rr * 1056 + boff[dx];                \
            s16x8 b0 = *(const s16x8*)bp;                                          \
            s16x8 b1 = *(const s16x8*)(bp + 512);                                  \
            const unsigned short* ap = (WC) + aoff + t * 16;                       \
            _Pragma("unroll") for (int mi = 0; mi < 4; ++mi) {                     \
                s16x8 av = *(const s16x8*)(ap + mi * 4608);                        \
                acc[mi][0] = __builtin_amdgcn_mfma_f32_32x32x16_bf16(av, b0, acc[mi][0], 0, 0, 0); \
                acc[mi][1] = __builtin_amdgcn_mfma_f32_32x32x16_bf16(av, b1, acc[mi][1], 0, 0, 0); \
            }                                                                      \
        }                                                                          \
    }

#define STEPSYNC()                                                                 \
    {                                                                              \
        asm volatile("s_waitcnt vmcnt(0)" ::: "memory");                           \
        __builtin_amdgcn_s_barrier();                                              \
        __builtin_amdgcn_sched_barrier(0);                                         \
    }

__global__ __launch_bounds__(512, 2)
void conv_kernel(const unsigned short* __restrict__ xs2,
                 const unsigned short* __restrict__ wb2,
                 const float* __restrict__ deco,
                 float* __restrict__ out) {
    extern __shared__ unsigned short smem[];
    unsigned short* w0 = smem;
    unsigned short* x0 = smem + W_SH;
    unsigned short* w1 = smem + W_SH + X_SH;
    unsigned short* x1 = smem + 2 * W_SH + X_SH;

    int tid  = threadIdx.x;
    int lane = tid & 63, wave = tid >> 6;
    int r31  = lane & 31, hi = lane >> 5;

    int blk = blockIdx.x;
    int bi = blk & 15, ot = (blk >> 4) & 3, yt = blk >> 6;
    int o0 = ot * 128, y0 = yt * 8;

    // zero X buffers once (halo cols + out-of-image rows stay 0 forever)
    {
        u32x4 z = {0u, 0u, 0u, 0u};
        for (int idx = tid; idx < X_SH / 8; idx += 512) {
            *(u32x4*)(x0 + idx * 8) = z;
            *(u32x4*)(x1 + idx * 8) = z;
        }
    }
    __syncthreads();

    const char* wsrc = (const char*)wb2 + (size_t)ot * 32 * 2304 * 16;
    const char* xsrc = (const char*)xs2 + (size_t)bi * 32 * 64 * 128 * 16;

    // per-lane read bases (XOR-swizzle folded in; bijective mod-8 slot phases)
    int g = hi;
    int aoff = r31 * 144 + (g ^ ((r31 >> 2) & 1)) * 8;   // shorts; + mi*4608 + t*16
    int boff[3];
    #pragma unroll
    for (int dx = 0; dx < 3; ++dx) {
        int cb = r31 + dx;
        boff[dx] = cb * 16 + (g ^ ((cb >> 2) & 1)) * 8;  // shorts; + rr*1056 + ni*512
    }

    f32x16 acc[4][2];
    #pragma unroll
    for (int mi = 0; mi < 4; ++mi)
        #pragma unroll
        for (int ni = 0; ni < 2; ++ni)
            #pragma unroll
            for (int k = 0; k < 16; ++k) acc[mi][ni][k] = 0.f;

    ISSUE(0, w0, x0);

    for (int c = 0; c < 32; c += 2) {
        STEPSYNC();                       // my chunk-c loads landed; all waves synced
        ISSUE(c + 1, w1, x1);             // prefetch next chunk (covered by compute)
        COMPUTE(w0, x0);
        STEPSYNC();
        if (c + 2 < 32) ISSUE(c + 2, w0, x0);
        COMPUTE(w1, x1);
    }

    // epilogue: scale by deco, store f32
    int y = y0 + wave;
    const float* dcp = deco + bi * NCH + o0;
    #pragma unroll
    for (int mi = 0; mi < 4; ++mi) {
        #pragma unroll
        for (int r = 0; r < 16; ++r) {
            int ol = mi * 32 + (r & 3) + 8 * (r >> 2) + 4 * hi;
            float dc = dcp[ol];
            float* orow = out + ((size_t)(bi * NCH + o0 + ol) * 64 + y) * 64 + r31;
            orow[0]  = acc[mi][0][r] * dc;
            orow[32] = acc[mi][1][r] * dc;
        }
    }
}

extern "C" void kernel_launch(void* const* d_in, const int* in_sizes, int n_in,
                              void* d_out, int out_size, void* d_ws, size_t ws_size,
                              hipStream_t stream) {
    const float* x      = (const float*)d_in[0];
    const float* style  = (const float*)d_in[1];
    const float* weight = (const float*)d_in[2];
    const float* fc_w   = (const float*)d_in[3];
    const float* fc_b   = (const float*)d_in[4];
    float* out = (float*)d_out;

    char* ws = (char*)d_ws;
    float* s    = (float*)(ws);
    float* deco = (float*)(ws + 32768);
    float* q    = (float*)(ws + 65536);
    unsigned short* wb2 = (unsigned short*)(ws + 1114112);
    unsigned short* xs2 = (unsigned short*)(ws + 5832704);

    (void)hipFuncSetAttribute((const void*)conv_kernel,
                              hipFuncAttributeMaxDynamicSharedMemorySize, 115968);

    calc_s_kernel<<<2048, 256, 0, stream>>>(style, fc_w, fc_b, s);
    calc_q_wb2_kernel<<<512, 512, 0, stream>>>(weight, q, wb2);
    calc_deco_kernel<<<2048, 256, 0, stream>>>(q, s, deco);
    scale_x2_kernel<<<512, 256, 0, stream>>>(x, s, xs2);
    conv_kernel<<<512, 512, 115968, stream>>>(xs2, wb2, deco, out);
}